// Round 9
// baseline (522.612 us; speedup 1.0000x reference)
//
#include <hip/hip_runtime.h>
#include <hip/hip_bf16.h>
#include <hip/hip_fp16.h>

constexpr int FDIM = 128;
#define HSCALE 16384.0f         // 2^14: |h|<1 -> scaled <16384 <= 65504, always safe
#define HSCALE_INV (1.0f/16384.0f)
#define ZSCALE 0.125f           // extra headroom for Zh = Hh @ W6
#define ZSCALE_COMP (HSCALE_INV * 8.0f)

typedef _Float16 f16x8 __attribute__((ext_vector_type(8)));
typedef float f32x4 __attribute__((ext_vector_type(4)));
typedef float f32x2 __attribute__((ext_vector_type(2)));

// ===================== atomic-free CSR build: 3-level MSD partition =====================
// record: [col:17 @47][row:17 @30][ew_f16 @0]   (col < 2^17 required; N=100000 ok)
constexpr int CHUNK = 4096;
constexpr int B1 = 64;
constexpr int B2 = 64;
constexpr int NC2 = 64;
constexpr int MAXC2 = 20;

__global__ __launch_bounds__(256) void k_p1hist(const int* __restrict__ col,
                                                int* __restrict__ cnt1, int E, int NB1)
{
    __shared__ int h[B1];
    int blk = blockIdx.x, t = threadIdx.x;
    if (t < B1) h[t] = 0;
    __syncthreads();
    int base = blk * CHUNK;
    for (int i = t; i < CHUNK; i += 256) {
        int g = base + i;
        if (g < E) atomicAdd(&h[col[g] >> 11], 1);
    }
    __syncthreads();
    if (t < B1) cnt1[t * NB1 + blk] = h[t];
}

__global__ __launch_bounds__(256) void k_blocksum(const int* __restrict__ cnt,
                                                  int* __restrict__ bsum, int n)
{
    __shared__ int s[256];
    int t = threadIdx.x;
    int i = blockIdx.x * 256 + t;
    s[t] = (i < n) ? cnt[i] : 0;
    __syncthreads();
    for (int o = 128; o > 0; o >>= 1) {
        if (t < o) s[t] += s[t + o];
        __syncthreads();
    }
    if (t == 0) bsum[blockIdx.x] = s[0];
}

__global__ __launch_bounds__(1024) void k_scan_bsum(const int* __restrict__ bsum,
                                                    int* __restrict__ boff, int nb,
                                                    int* __restrict__ out, int n, int total)
{
    __shared__ int s[1024];
    int t = threadIdx.x;
    int v = (t < nb) ? bsum[t] : 0;
    s[t] = v;
    __syncthreads();
    for (int o = 1; o < 1024; o <<= 1) {
        int u = (t >= o) ? s[t - o] : 0;
        __syncthreads();
        s[t] += u;
        __syncthreads();
    }
    if (t < nb) boff[t] = s[t] - v;   // exclusive
    if (t == 0) out[n] = total;
}

__global__ __launch_bounds__(256) void k_offsets(const int* __restrict__ cnt,
                                                 const int* __restrict__ boff,
                                                 int* __restrict__ out, int n)
{
    __shared__ int s[256];
    int t = threadIdx.x;
    int i = blockIdx.x * 256 + t;
    int v = (i < n) ? cnt[i] : 0;
    s[t] = v;
    __syncthreads();
    for (int o = 1; o < 256; o <<= 1) {
        int u = (t >= o) ? s[t - o] : 0;
        __syncthreads();
        s[t] += u;
        __syncthreads();
    }
    if (i < n) out[i] = boff[blockIdx.x] + s[t] - v;
}

__global__ __launch_bounds__(256) void k_p1part(const int* __restrict__ col,
                                                const int* __restrict__ row,
                                                const float* __restrict__ ew,
                                                const int* __restrict__ cnt1,
                                                const int* __restrict__ scan1,
                                                unsigned long long* __restrict__ rec1,
                                                int E, int NB1)
{
    __shared__ unsigned long long stage[CHUNK];
    __shared__ int hcnt[B1], lb[B1], gb[B1], cur[B1];
    int blk = blockIdx.x, t = threadIdx.x;
    if (t < B1) {
        hcnt[t] = cnt1[t * NB1 + blk];
        gb[t]   = scan1[t * NB1 + blk];
    }
    __syncthreads();
    if (t == 0) {
        int run = 0;
        for (int b = 0; b < B1; ++b) { lb[b] = run; run += hcnt[b]; }
    }
    __syncthreads();
    if (t < B1) cur[t] = lb[t];
    __syncthreads();
    int base = blk * CHUNK;
    for (int i = t; i < CHUNK; i += 256) {
        int g = base + i;
        if (g < E) {
            int c = col[g], r = row[g];
            unsigned long long rc = ((unsigned long long)c << 47) |
                                    ((unsigned long long)r << 30) |
                                    (unsigned long long)__half_as_ushort(__float2half(ew[g]));
            int p = atomicAdd(&cur[c >> 11], 1);
            stage[p] = rc;
        }
    }
    __syncthreads();
    int here = min(CHUNK, E - base);
    for (int j = t; j < here; j += 256) {
        unsigned long long rc = stage[j];
        int b = (int)(rc >> 58);
        rec1[gb[b] + (j - lb[b])] = rc;
    }
}

__global__ __launch_bounds__(256) void k_p2hist(const unsigned long long* __restrict__ rec1,
                                                const int* __restrict__ scan1,
                                                int* __restrict__ cnt2, int NB1)
{
    __shared__ int h[B2];
    int b = blockIdx.x / MAXC2, ci = blockIdx.x % MAXC2, t = threadIdx.x;
    int S1 = scan1[b * NB1];
    int S2 = scan1[(b + 1) * NB1];
    int size = S2 - S1;
    for (int c = ci; c * CHUNK < size && c < NC2; c += MAXC2) {
        __syncthreads();
        if (t < B2) h[t] = 0;
        __syncthreads();
        int cb = S1 + c * CHUNK, ce = min(cb + CHUNK, S2);
        for (int i = cb + t; i < ce; i += 256)
            atomicAdd(&h[(int)((rec1[i] >> 52) & 63)], 1);
        __syncthreads();
        if (t < B2) cnt2[(b * B2 + t) * NC2 + c] = h[t];
    }
}

__global__ __launch_bounds__(256) void k_p2part(const unsigned long long* __restrict__ rec1,
                                                const int* __restrict__ scan1,
                                                const int* __restrict__ cnt2,
                                                const int* __restrict__ scan2,
                                                unsigned long long* __restrict__ rec2, int NB1)
{
    __shared__ unsigned long long stage[CHUNK];
    __shared__ int hcnt[B2], lb[B2], gb[B2], cur[B2];
    int b = blockIdx.x / MAXC2, ci = blockIdx.x % MAXC2, t = threadIdx.x;
    int S1 = scan1[b * NB1];
    int S2 = scan1[(b + 1) * NB1];
    int size = S2 - S1;
    for (int c = ci; c * CHUNK < size && c < NC2; c += MAXC2) {
        __syncthreads();
        if (t < B2) {
            hcnt[t] = cnt2[(b * B2 + t) * NC2 + c];
            gb[t]   = scan2[(b * B2 + t) * NC2 + c];
        }
        __syncthreads();
        if (t == 0) {
            int run = 0;
            for (int sb = 0; sb < B2; ++sb) { lb[sb] = run; run += hcnt[sb]; }
        }
        __syncthreads();
        if (t < B2) cur[t] = lb[t];
        __syncthreads();
        int cb = S1 + c * CHUNK, ce = min(cb + CHUNK, S2);
        for (int i = cb + t; i < ce; i += 256) {
            unsigned long long rc = rec1[i];
            int p = atomicAdd(&cur[(int)((rc >> 52) & 63)], 1);
            stage[p] = rc;
        }
        __syncthreads();
        int here = ce - cb;
        for (int j = t; j < here; j += 256) {
            unsigned long long rc = stage[j];
            int sb = (int)((rc >> 52) & 63);
            rec2[gb[sb] + (j - lb[sb])] = rc;
        }
    }
}

// final: counting sort per 32-node sub-bucket.
__global__ __launch_bounds__(256) void k_p3(const unsigned long long* __restrict__ rec2,
                                            const int* __restrict__ scan2,
                                            int2* __restrict__ ep, int* __restrict__ off,
                                            float* __restrict__ dis, int N, int E)
{
    __shared__ int h[32], lb[32], cur[32];
    __shared__ float dg[32], sdis[32];
    int g = blockIdx.x, t = threadIdx.x;
    int S1 = scan2[g * NC2];
    int S2 = scan2[(g + 1) * NC2];
    if (t < 32) { h[t] = 0; dg[t] = 0.f; }
    __syncthreads();
    for (int i = S1 + t; i < S2; i += 256) {
        unsigned long long rc = rec2[i];
        int nl = (int)((rc >> 47) & 31);
        atomicAdd(&h[nl], 1);
        atomicAdd(&dg[nl], __half2float(__ushort_as_half((unsigned short)(rc & 0xFFFF))));
    }
    __syncthreads();
    if (t == 0) {
        int run = S1;
        for (int k = 0; k < 32; ++k) { lb[k] = run; run += h[k]; }
    }
    __syncthreads();
    if (t < 32) {
        cur[t] = lb[t];
        sdis[t] = 1.0f / sqrtf(dg[t] + 1.0f);   // self-loop included; >= 1 always
        int node = g * 32 + t;
        if (node < N) { off[node] = lb[t]; dis[node] = sdis[t]; }
    }
    if (g == 0 && t == 0) off[N] = E;
    __syncthreads();
    for (int i = S1 + t; i < S2; i += 256) {
        unsigned long long rc = rec2[i];
        int nl = (int)((rc >> 47) & 31);
        int p = atomicAdd(&cur[nl], 1);
        float w = __half2float(__ushort_as_half((unsigned short)(rc & 0xFFFF))) * sdis[nl];
        ep[p] = make_int2((int)((rc >> 30) & 0x1FFFF), __float_as_int(w));
    }
}

// ---------------- f32 -> f16 convert with dis[row] pre-scale (stage A table) ----------------
__global__ __launch_bounds__(256) void k_cvt(const float4* __restrict__ in,
                                             const float* __restrict__ dis,
                                             __half2* __restrict__ out, int n4)
{
    int i = blockIdx.x * 256 + threadIdx.x;
    if (i >= n4) return;
    float4 v = in[i];
    float d = dis[i >> 5];          // 32 float4 per row
    __half2 a = __floats2half2_rn(v.x * d, v.y * d);
    __half2 b = __floats2half2_rn(v.z * d, v.w * d);
    float2 pk;
    ((__half2*)&pk)[0] = a;
    ((__half2*)&pk)[1] = b;
    *(float2*)&out[(size_t)i * 2] = pk;
}

// ---------------- W (f32 [128][N]) -> Wt (f16 [N][128]) transpose ----------------
__global__ __launch_bounds__(256) void k_wt(const float* __restrict__ W,
                                            __half* __restrict__ Wt, int N)
{
    int idx = blockIdx.x * 256 + threadIdx.x;
    if (idx >= N * 128) return;
    int n = idx >> 7, k = idx & 127;
    Wt[idx] = __float2half(W[(size_t)k * N + n]);
}

// ---------------- SpMM: Yh = fp16(aggregate), 2 edges per wave-step ----------------
// Lanes 0-31 take even edges, 32-63 odd edges; each lane gathers 8B (4 features).
// Parity partials merged with shfl_xor(32) at the end. f32x2 accs -> v_pk_fma_f32.
__global__ __launch_bounds__(256) void k_spmm(const __half2* __restrict__ Xh,
                                              const int2* __restrict__ ep,
                                              const int* __restrict__ off,
                                              const float* __restrict__ dis,
                                              __half2* __restrict__ Yh, int n)
{
    int gt = blockIdx.x * 256 + threadIdx.x;
    int node = gt >> 6;
    int lane = threadIdx.x & 63;
    if (node >= n) return;
    const int half = lane >> 5;
    const int l31 = lane & 31;
    const char* Xb = (const char*)Xh;
    const unsigned loff = (unsigned)l31 << 3;

    f32x2 p0a = {0.f, 0.f}, p0b = {0.f, 0.f};   // pairs j=0,2
    f32x2 p1a = {0.f, 0.f}, p1b = {0.f, 0.f};   // pairs j=1,3

    if (half == 0) {                            // self-loop term, even half only
        float sn = dis[node];
        float2 raw = *(const float2*)(Xb + ((unsigned)node << 8) + loff);
        float2 f0 = __half22float2(((const __half2*)&raw)[0]);
        float2 f1 = __half22float2(((const __half2*)&raw)[1]);
        p0a.x = sn * f0.x; p0a.y = sn * f0.y;
        p0b.x = sn * f1.x; p0b.y = sn * f1.y;
    }

    const int e0 = off[node];
    const int cnt = off[node + 1] - e0;
    const int2* el = ep + e0;
    const int nb = cnt >> 3;                    // batches of 8 edges = 4 pairs
    int done = 0;

#define SPMM_FMA(XV, WV)                                                     \
    {                                                                        \
        _Pragma("unroll")                                                    \
        for (int j = 0; j < 4; ++j) {                                        \
            float2 f0 = __half22float2(((const __half2*)&XV[j])[0]);         \
            float2 f1 = __half22float2(((const __half2*)&XV[j])[1]);         \
            f32x2 wv = {WV[j], WV[j]};                                       \
            f32x2 v0 = {f0.x, f0.y}, v1 = {f1.x, f1.y};                      \
            if (j & 1) { p1a += wv * v0; p1b += wv * v1; }                   \
            else       { p0a += wv * v0; p0b += wv * v1; }                   \
        }                                                                    \
    }

    if (nb >= 2) {
        int2 en[4];
        float2 xc[4], g[4];
        float wc[4], w2[4];
        {
            int2 ec[4];
            #pragma unroll
            for (int j = 0; j < 4; ++j) ec[j] = el[2 * j + half];
            #pragma unroll
            for (int j = 0; j < 4; ++j)
                xc[j] = *(const float2*)(Xb + ((unsigned)ec[j].x << 8) + loff);
            #pragma unroll
            for (int j = 0; j < 4; ++j) wc[j] = __int_as_float(ec[j].y);
        }
        #pragma unroll
        for (int j = 0; j < 4; ++j) en[j] = el[8 + 2 * j + half];

        #pragma unroll 2
        for (int b = 0; b + 2 < nb; ++b) {
            #pragma unroll
            for (int j = 0; j < 4; ++j)
                g[j] = *(const float2*)(Xb + ((unsigned)en[j].x << 8) + loff);
            #pragma unroll
            for (int j = 0; j < 4; ++j) w2[j] = __int_as_float(en[j].y);
            const int2* eb = el + (b + 2) * 8;
            #pragma unroll
            for (int j = 0; j < 4; ++j) en[j] = eb[2 * j + half];
            SPMM_FMA(xc, wc);
            #pragma unroll
            for (int j = 0; j < 4; ++j) { xc[j] = g[j]; wc[j] = w2[j]; }
        }
        // epilogue: batch nb-2 (xc) then nb-1 (en)
        #pragma unroll
        for (int j = 0; j < 4; ++j)
            g[j] = *(const float2*)(Xb + ((unsigned)en[j].x << 8) + loff);
        #pragma unroll
        for (int j = 0; j < 4; ++j) w2[j] = __int_as_float(en[j].y);
        SPMM_FMA(xc, wc);
        SPMM_FMA(g, w2);
        done = nb * 8;
    }
    // pair tail (handles 0..7 leftover edges)
    for (int e = done; e < cnt; e += 2) {
        int idx = e + half;
        int idc = min(idx, cnt - 1);
        int2 pe = el[idc];
        float w = (idx < cnt) ? __int_as_float(pe.y) : 0.f;
        float2 raw = *(const float2*)(Xb + ((unsigned)pe.x << 8) + loff);
        float2 f0 = __half22float2(((const __half2*)&raw)[0]);
        float2 f1 = __half22float2(((const __half2*)&raw)[1]);
        f32x2 wv = {w, w};
        f32x2 v0 = {f0.x, f0.y}, v1 = {f1.x, f1.y};
        p0a += wv * v0; p0b += wv * v1;
    }
#undef SPMM_FMA

    float r0 = p0a.x + p1a.x, r1 = p0a.y + p1a.y;
    float r2 = p0b.x + p1b.x, r3 = p0b.y + p1b.y;
    r0 += __shfl_xor(r0, 32);
    r1 += __shfl_xor(r1, 32);
    r2 += __shfl_xor(r2, 32);
    r3 += __shfl_xor(r3, 32);
    if (half == 0) {
        float2 pk;
        ((__half2*)&pk)[0] = __floats2half2_rn(r0, r1);
        ((__half2*)&pk)[1] = __floats2half2_rn(r2, r3);
        *(float2*)((char*)Yh + ((unsigned)node << 8) + loff) = pk;
    }
}

// ---------------- SpMM64 (stage C): 64-feature rows, 2 edges per wave-step ----------------
// Lane gathers 4B (2 features); parity merge via shfl_xor(32); fused tanh+bias, fp32 out.
__global__ __launch_bounds__(256) void k_spmm64(const __half* __restrict__ Zh,
                                                const int2* __restrict__ ep,
                                                const int* __restrict__ off,
                                                const float* __restrict__ dis,
                                                const float* __restrict__ b6,
                                                float* __restrict__ out, int n)
{
    int gt = blockIdx.x * 256 + threadIdx.x;
    int node = gt >> 6;
    int lane = threadIdx.x & 63;
    if (node >= n) return;
    const int half = lane >> 5;
    const int l31 = lane & 31;
    const char* Zb = (const char*)Zh;
    const unsigned loff = (unsigned)l31 << 2;

    f32x2 p0 = {0.f, 0.f}, p1 = {0.f, 0.f};

    if (half == 0) {
        float sn = dis[node];
        __half2 raw = *(const __half2*)(Zb + ((unsigned)node << 7) + loff);
        float2 f0 = __half22float2(raw);
        p0.x = sn * f0.x; p0.y = sn * f0.y;
    }

    const int e0 = off[node];
    const int cnt = off[node + 1] - e0;
    const int2* el = ep + e0;
    const int nb = cnt >> 3;
    int done = 0;

#define SPMM64_FMA(XV, WV)                                                   \
    {                                                                        \
        _Pragma("unroll")                                                    \
        for (int j = 0; j < 4; ++j) {                                        \
            float2 f0 = __half22float2(XV[j]);                               \
            f32x2 wv = {WV[j], WV[j]};                                       \
            f32x2 v0 = {f0.x, f0.y};                                         \
            if (j & 1) p1 += wv * v0; else p0 += wv * v0;                    \
        }                                                                    \
    }

    if (nb >= 2) {
        int2 en[4];
        __half2 xc[4], g[4];
        float wc[4], w2[4];
        {
            int2 ec[4];
            #pragma unroll
            for (int j = 0; j < 4; ++j) ec[j] = el[2 * j + half];
            #pragma unroll
            for (int j = 0; j < 4; ++j)
                xc[j] = *(const __half2*)(Zb + ((unsigned)ec[j].x << 7) + loff);
            #pragma unroll
            for (int j = 0; j < 4; ++j) wc[j] = __int_as_float(ec[j].y);
        }
        #pragma unroll
        for (int j = 0; j < 4; ++j) en[j] = el[8 + 2 * j + half];

        #pragma unroll 2
        for (int b = 0; b + 2 < nb; ++b) {
            #pragma unroll
            for (int j = 0; j < 4; ++j)
                g[j] = *(const __half2*)(Zb + ((unsigned)en[j].x << 7) + loff);
            #pragma unroll
            for (int j = 0; j < 4; ++j) w2[j] = __int_as_float(en[j].y);
            const int2* eb = el + (b + 2) * 8;
            #pragma unroll
            for (int j = 0; j < 4; ++j) en[j] = eb[2 * j + half];
            SPMM64_FMA(xc, wc);
            #pragma unroll
            for (int j = 0; j < 4; ++j) { xc[j] = g[j]; wc[j] = w2[j]; }
        }
        #pragma unroll
        for (int j = 0; j < 4; ++j)
            g[j] = *(const __half2*)(Zb + ((unsigned)en[j].x << 7) + loff);
        #pragma unroll
        for (int j = 0; j < 4; ++j) w2[j] = __int_as_float(en[j].y);
        SPMM64_FMA(xc, wc);
        SPMM64_FMA(g, w2);
        done = nb * 8;
    }
    for (int e = done; e < cnt; e += 2) {
        int idx = e + half;
        int idc = min(idx, cnt - 1);
        int2 pe = el[idc];
        float w = (idx < cnt) ? __int_as_float(pe.y) : 0.f;
        __half2 raw = *(const __half2*)(Zb + ((unsigned)pe.x << 7) + loff);
        float2 f0 = __half22float2(raw);
        f32x2 wv = {w, w};
        f32x2 v0 = {f0.x, f0.y};
        p0 += wv * v0;
    }
#undef SPMM64_FMA

    float r0 = p0.x + p1.x, r1 = p0.y + p1.y;
    r0 += __shfl_xor(r0, 32);
    r1 += __shfl_xor(r1, 32);
    if (half == 0) {
        float2 bb = *(const float2*)(b6 + 2 * l31);
        float2 o;
        o.x = tanhf(fmaf(r0, ZSCALE_COMP, bb.x));
        o.y = tanhf(fmaf(r1, ZSCALE_COMP, bb.y));
        *(float2*)((char*)out + ((unsigned)node << 8) + ((unsigned)l31 << 3)) = o;
    }
}

// fast tanh: 1 - 2/(e^{2x}+1) via v_exp + v_rcp
__device__ __forceinline__ float fast_tanh(float x) {
    float e = __expf(2.0f * x);
    return 1.0f - 2.0f * __builtin_amdgcn_rcpf(e + 1.0f);
}

// ---------------- MFMA GEMM, register-resident B (round-8 proven) ----------------
template <int FOUT, int NW, bool ACT>
__global__ __launch_bounds__(256, 2) void k_mgemm(const __half* __restrict__ Yh,
                                                  float IS, float OS,
                                                  const float* __restrict__ dis,
                                                  const __half* __restrict__ Wt0, const float* __restrict__ B0,
                                                  const __half* __restrict__ Wt1, const float* __restrict__ B1,
                                                  const __half* __restrict__ Wt2, const float* __restrict__ B2,
                                                  __half* __restrict__ Out, int nRows)
{
    constexpr int NF = FOUT / 16;
    constexpr int FPW = NF / 4;
    int tid = threadIdx.x;
    int wv = tid >> 6;
    int lane = tid & 63;
    int lo = lane & 15, hi = lane >> 4;
    int r0 = blockIdx.x * 64;

    const __half* Wts[3] = {Wt0, Wt1, Wt2};
    const float*  Bs[3]  = {B0, B1, B2};

    f16x8 bfr[FPW][NW][4];
    float bias[FPW][NW];
    #pragma unroll
    for (int fp = 0; fp < FPW; ++fp) {
        int f = wv * FPW + fp;
        #pragma unroll
        for (int w = 0; w < NW; ++w) {
            const __half* Bp = Wts[w] + (size_t)(f * 16 + lo) * 128 + hi * 8;
            #pragma unroll
            for (int ks = 0; ks < 4; ++ks)
                bfr[fp][w][ks] = *(const f16x8*)(Bp + ks * 32);
            if constexpr (ACT) bias[fp][w] = Bs[w][f * 16 + lo];
        }
    }

    float disr[4][4];
    if constexpr (ACT) {
        #pragma unroll
        for (int rt = 0; rt < 4; ++rt)
            #pragma unroll
            for (int r = 0; r < 4; ++r) {
                int row = r0 + rt * 16 + hi * 4 + r;
                if (row >= nRows) row = nRows - 1;
                disr[rt][r] = dis[row];
            }
    }

    f16x8 a[4], an[4];
    {
        int row = r0 + lo;
        if (row >= nRows) row = nRows - 1;
        const __half* Ap = Yh + (size_t)row * 128 + hi * 8;
        #pragma unroll
        for (int ks = 0; ks < 4; ++ks) a[ks] = *(const f16x8*)(Ap + ks * 32);
    }

    #pragma unroll
    for (int rt = 0; rt < 4; ++rt) {
        if (rt < 3) {
            int row = r0 + (rt + 1) * 16 + lo;
            if (row >= nRows) row = nRows - 1;
            const __half* Ap = Yh + (size_t)row * 128 + hi * 8;
            #pragma unroll
            for (int ks = 0; ks < 4; ++ks) an[ks] = *(const f16x8*)(Ap + ks * 32);
        }
        #pragma unroll
        for (int fp = 0; fp < FPW; ++fp) {
            f32x4 ac0 = {0.f, 0.f, 0.f, 0.f};
            f32x4 ac1 = {0.f, 0.f, 0.f, 0.f};
            f32x4 ac2 = {0.f, 0.f, 0.f, 0.f};
            #pragma unroll
            for (int ks = 0; ks < 4; ++ks) {
                ac0 = __builtin_amdgcn_mfma_f32_16x16x32_f16(a[ks], bfr[fp][0][ks], ac0, 0, 0, 0);
                if constexpr (NW > 1)
                    ac1 = __builtin_amdgcn_mfma_f32_16x16x32_f16(a[ks], bfr[fp][1][ks], ac1, 0, 0, 0);
                if constexpr (NW > 2)
                    ac2 = __builtin_amdgcn_mfma_f32_16x16x32_f16(a[ks], bfr[fp][2][ks], ac2, 0, 0, 0);
            }
            int c = (wv * FPW + fp) * 16 + lo;
            #pragma unroll
            for (int r = 0; r < 4; ++r) {
                int row = r0 + rt * 16 + hi * 4 + r;
                float v;
                if constexpr (ACT) {
                    v = fast_tanh(fmaf(ac0[r], IS, bias[fp][0]));
                    if constexpr (NW > 1) v *= fast_tanh(fmaf(ac1[r], IS, bias[fp][1]));
                    if constexpr (NW > 2) v *= fast_tanh(fmaf(ac2[r], IS, bias[fp][2]));
                    v *= OS * disr[rt][r];
                } else {
                    v = ac0[r] * OS;
                }
                if (row < nRows)
                    Out[(size_t)row * FOUT + c] = __float2half(v);
            }
        }
        #pragma unroll
        for (int ks = 0; ks < 4; ++ks) a[ks] = an[ks];
    }
}

extern "C" void kernel_launch(void* const* d_in, const int* in_sizes, int n_in,
                              void* d_out, int out_size, void* d_ws, size_t ws_size,
                              hipStream_t stream)
{
    const float* h0 = (const float*)d_in[0];
    const int*   ei = (const int*)d_in[1];
    const float* ew = (const float*)d_in[2];
    const float* W1 = (const float*)d_in[3];  const float* b1 = (const float*)d_in[4];
    const float* W2 = (const float*)d_in[5];  const float* b2 = (const float*)d_in[6];
    const float* W3 = (const float*)d_in[7];  const float* b3 = (const float*)d_in[8];
    const float* W4 = (const float*)d_in[9];  const float* b4 = (const float*)d_in[10];
    const float* W5 = (const float*)d_in[11]; const float* b5 = (const float*)d_in[12];
    const float* W6 = (const float*)d_in[13]; const float* b6 = (const float*)d_in[14];

    const int N = in_sizes[0] / FDIM;
    const int E = in_sizes[2];
    const int* rowp = ei;
    const int* colp = ei + E;

    const int NB1 = (E + CHUNK - 1) / CHUNK;
    const int n1  = B1 * NB1;
    const int n2  = B1 * B2 * NC2;
    const int NBs1 = (n1 + 255) / 256;
    const int NBs2 = (n2 + 255) / 256;

    char* p = (char*)d_ws;
    auto alloc = [&](size_t bytes) -> void* {
        void* r = (void*)p;
        p += (bytes + 255) & ~(size_t)255;
        return r;
    };
    int* cnt1  = (int*)alloc((size_t)(n1 + 1) * 4);
    int* scan1 = (int*)alloc((size_t)(n1 + 1) * 4);
    int* cnt2  = (int*)alloc((size_t)(n2 + 1) * 4);
    int* scan2 = (int*)alloc((size_t)(n2 + 1) * 4);
    int* bsum  = (int*)alloc((size_t)1024 * 4);
    int* boff  = (int*)alloc((size_t)1024 * 4);
    int* off   = (int*)alloc((size_t)(N + 1) * 4);
    float* dis = (float*)alloc((size_t)N * 4);
    unsigned long long* rec1 = (unsigned long long*)alloc((size_t)(E + 16) * 8);  // aliased by ep
    unsigned long long* rec2 = (unsigned long long*)alloc((size_t)E * 8);         // aliased by Yh
    __half2* Xh = (__half2*)alloc((size_t)N * FDIM * 2);                          // aliased by Zh
    __half2* Hh = (__half2*)alloc((size_t)N * FDIM * 2);
    __half* W1t = (__half*)alloc((size_t)128 * 128 * 2);
    __half* W2t = (__half*)alloc((size_t)128 * 128 * 2);
    __half* W3t = (__half*)alloc((size_t)128 * 128 * 2);
    __half* W4t = (__half*)alloc((size_t)128 * 128 * 2);
    __half* W5t = (__half*)alloc((size_t)128 * 128 * 2);
    __half* W6t = (__half*)alloc((size_t)64 * 128 * 2);

    int2*    ep = (int2*)rec1;       // rec1 dead after k_p2part
    __half2* Yh = (__half2*)rec2;    // rec2 dead after k_p3
    __half*  Zh = (__half*)Xh;       // Xh dead after stage-A spmm

    hipMemsetAsync(cnt2, 0, (size_t)(n2 + 1) * 4, stream);

    // ---- build (atomic-free, emits ep with dis[col] folded + dis[]) ----
    k_p1hist<<<NB1, 256, 0, stream>>>(colp, cnt1, E, NB1);
    k_blocksum<<<NBs1, 256, 0, stream>>>(cnt1, bsum, n1);
    k_scan_bsum<<<1, 1024, 0, stream>>>(bsum, boff, NBs1, scan1, n1, E);
    k_offsets<<<NBs1, 256, 0, stream>>>(cnt1, boff, scan1, n1);
    k_p1part<<<NB1, 256, 0, stream>>>(colp, rowp, ew, cnt1, scan1, rec1, E, NB1);
    k_p2hist<<<B1 * MAXC2, 256, 0, stream>>>(rec1, scan1, cnt2, NB1);
    k_blocksum<<<NBs2, 256, 0, stream>>>(cnt2, bsum, n2);
    k_scan_bsum<<<1, 1024, 0, stream>>>(bsum, boff, NBs2, scan2, n2, E);
    k_offsets<<<NBs2, 256, 0, stream>>>(cnt2, boff, scan2, n2);
    k_p2part<<<B1 * MAXC2, 256, 0, stream>>>(rec1, scan1, cnt2, scan2, rec2, NB1);
    k_p3<<<B1 * B2, 256, 0, stream>>>(rec2, scan2, ep, off, dis, N, E);

    // ---- dense prep (k_cvt needs dis) ----
    k_cvt<<<(N * 32 + 255) / 256, 256, 0, stream>>>((const float4*)h0, dis, Xh, N * 32);
    k_wt<<<64, 256, 0, stream>>>(W1, W1t, 128);
    k_wt<<<64, 256, 0, stream>>>(W2, W2t, 128);
    k_wt<<<64, 256, 0, stream>>>(W3, W3t, 128);
    k_wt<<<64, 256, 0, stream>>>(W4, W4t, 128);
    k_wt<<<64, 256, 0, stream>>>(W5, W5t, 128);
    k_wt<<<32, 256, 0, stream>>>(W6, W6t, 64);

    const int sb = (N + 3) / 4;     // 4 waves (nodes) per 256-thread block
    const int gb = (N + 63) / 64;   // 64-row tiles

    // Stage A: Yh = agg(Xh) ; Hh = HSCALE*dis*tanh(YhW1+b1)*tanh(YhW2+b2)*tanh(YhW3+b3)
    k_spmm<<<sb, 256, 0, stream>>>(Xh, ep, off, dis, Yh, N);
    k_mgemm<128, 3, true><<<gb, 256, 0, stream>>>((const __half*)Yh, 1.0f, HSCALE, dis,
        W1t, b1, W2t, b2, W3t, b3, (__half*)Hh, N);
    // Stage B: Yh = agg(Hh) ; Hh = HSCALE*dis*tanh(2^-14 YhW4+b4)*tanh(2^-14 YhW5+b5)
    k_spmm<<<sb, 256, 0, stream>>>(Hh, ep, off, dis, Yh, N);
    k_mgemm<128, 2, true><<<gb, 256, 0, stream>>>((const __half*)Yh, HSCALE_INV, HSCALE, dis,
        W4t, b4, W5t, b5, nullptr, nullptr, (__half*)Hh, N);
    // Stage C: project first (Zh = ZSCALE * Hh W6, 64 features), then aggregate+tanh -> out
    k_mgemm<64, 1, false><<<gb, 256, 0, stream>>>((const __half*)Hh, 1.0f, ZSCALE, nullptr,
        W6t, b6, nullptr, nullptr, nullptr, nullptr, Zh, N);
    k_spmm64<<<sb, 256, 0, stream>>>(Zh, ep, off, dis, b6, (float*)d_out, N);
}

// Round 10
// 502.714 us; speedup vs baseline: 1.0396x; 1.0396x over previous
//
#include <hip/hip_runtime.h>
#include <hip/hip_bf16.h>
#include <hip/hip_fp16.h>

constexpr int FDIM = 128;
#define HSCALE 16384.0f         // 2^14: |h|<1 -> scaled <16384 <= 65504, always safe
#define HSCALE_INV (1.0f/16384.0f)
#define ZSCALE 0.125f           // extra headroom for Zh = Hh @ W6
#define ZSCALE_COMP (HSCALE_INV * 8.0f)

typedef _Float16 f16x8 __attribute__((ext_vector_type(8)));
typedef float f32x4 __attribute__((ext_vector_type(4)));
typedef unsigned long long ull;

// ===================== atomic-reserved CSR build (2 partition passes) =====================
// record: [col:17 @47][row:17 @30][ew_f16 @0]
// level1: col>>11 (64 buckets, fixed-capacity regions, atomic reserve)
// level2: (col>>5)&63 (4096 groups of 32 cols, fixed-capacity, atomic reserve)
// then: 1-block scan of group sizes -> compact bases; p3 counting sort -> ep/off/dis
constexpr int CHUNK = 4096;
constexpr int B1 = 64;
constexpr int B2 = 64;
constexpr int NGRP = B1 * B2;   // 4096
constexpr int MAXC2 = 20;

__global__ __launch_bounds__(256) void k_init(int* __restrict__ cur1,
                                              int* __restrict__ cur2,
                                              int cap1, int cap2)
{
    int i = blockIdx.x * 256 + threadIdx.x;
    if (i < B1) cur1[i] = i * cap1;
    if (i < NGRP) cur2[i] = i * cap2;
}

// pass 1: chunk -> 64 coarse buckets. Records held in registers (16/thread),
// LDS hist, one global atomic reserve per bucket, LDS-staged coalesced writes.
__global__ __launch_bounds__(256) void k_p1part(const int* __restrict__ col,
                                                const int* __restrict__ row,
                                                const float* __restrict__ ew,
                                                int* __restrict__ cur1,
                                                ull* __restrict__ rec1, int E)
{
    __shared__ ull stage[CHUNK];
    __shared__ int hcnt[B1], lb[B1], gb[B1], lcur[B1];
    int blk = blockIdx.x, t = threadIdx.x;
    if (t < B1) hcnt[t] = 0;
    __syncthreads();
    int base = blk * CHUNK;
    ull rc[16];
    #pragma unroll
    for (int it = 0; it < 16; ++it) {
        int g = base + it * 256 + t;
        if (g < E) {
            int c = col[g], r = row[g];
            rc[it] = ((ull)c << 47) | ((ull)r << 30) |
                     (ull)__half_as_ushort(__float2half(ew[g]));
            atomicAdd(&hcnt[c >> 11], 1);
        } else rc[it] = ~0ull;
    }
    __syncthreads();
    if (t == 0) {
        int run = 0;
        for (int b = 0; b < B1; ++b) { lb[b] = run; run += hcnt[b]; }
    }
    __syncthreads();
    if (t < B1) { lcur[t] = lb[t]; gb[t] = atomicAdd(&cur1[t], hcnt[t]); }
    __syncthreads();
    #pragma unroll
    for (int it = 0; it < 16; ++it) {
        if (rc[it] != ~0ull) {
            int b = (int)(rc[it] >> 58);
            stage[atomicAdd(&lcur[b], 1)] = rc[it];
        }
    }
    __syncthreads();
    int here = min(CHUNK, E - base);
    for (int j = t; j < here; j += 256) {
        ull v = stage[j];
        int b = (int)(v >> 58);
        rec1[gb[b] + (j - lb[b])] = v;
    }
}

// pass 2: within each coarse bucket, partition chunks into 64 sub-buckets (groups).
__global__ __launch_bounds__(256) void k_p2part(const ull* __restrict__ rec1,
                                                const int* __restrict__ cur1,
                                                int* __restrict__ cur2,
                                                ull* __restrict__ rec2,
                                                int cap1)
{
    __shared__ ull stage[CHUNK];
    __shared__ int hcnt[B2], lb[B2], gb[B2], lcur[B2];
    int b = blockIdx.x / MAXC2, ci = blockIdx.x % MAXC2, t = threadIdx.x;
    int S1 = b * cap1;
    int size = cur1[b] - S1;
    for (int c = ci; c * CHUNK < size; c += MAXC2) {
        int cb = S1 + c * CHUNK;
        int m = min(CHUNK, size - c * CHUNK);
        __syncthreads();
        if (t < B2) hcnt[t] = 0;
        __syncthreads();
        ull rc[16];
        #pragma unroll
        for (int it = 0; it < 16; ++it) {
            int j = it * 256 + t;
            if (j < m) {
                ull v = rec1[cb + j];
                rc[it] = v;
                atomicAdd(&hcnt[(int)((v >> 52) & 63)], 1);
            } else rc[it] = ~0ull;
        }
        __syncthreads();
        if (t == 0) {
            int run = 0;
            for (int s = 0; s < B2; ++s) { lb[s] = run; run += hcnt[s]; }
        }
        __syncthreads();
        if (t < B2) { lcur[t] = lb[t]; gb[t] = atomicAdd(&cur2[b * B2 + t], hcnt[t]); }
        __syncthreads();
        #pragma unroll
        for (int it = 0; it < 16; ++it) {
            if (rc[it] != ~0ull) {
                int s = (int)((rc[it] >> 52) & 63);
                stage[atomicAdd(&lcur[s], 1)] = rc[it];
            }
        }
        __syncthreads();
        for (int j = t; j < m; j += 256) {
            ull v = stage[j];
            int s = (int)((v >> 52) & 63);
            rec2[gb[s] + (j - lb[s])] = v;
        }
    }
}

// one-block exclusive scan of the 4096 group sizes -> compact output bases
__global__ __launch_bounds__(1024) void k_gscan(const int* __restrict__ cur2,
                                                int* __restrict__ gbase, int cap2)
{
    __shared__ int s[1024];
    __shared__ int carry;
    int t = threadIdx.x;
    if (t == 0) carry = 0;
    __syncthreads();
    for (int tile = 0; tile < 4; ++tile) {
        int g = tile * 1024 + t;
        int v = cur2[g] - g * cap2;
        s[t] = v;
        __syncthreads();
        for (int o = 1; o < 1024; o <<= 1) {
            int u = (t >= o) ? s[t - o] : 0;
            __syncthreads();
            s[t] += u;
            __syncthreads();
        }
        gbase[g] = carry + s[t] - v;    // exclusive
        __syncthreads();
        if (t == 1023) carry += s[t];
        __syncthreads();
    }
}

// final: counting sort per 32-node group; emits compact ep=(row, ew*dis[col]), off, dis
__global__ __launch_bounds__(256) void k_p3(const ull* __restrict__ rec2,
                                            const int* __restrict__ cur2,
                                            const int* __restrict__ gbase,
                                            int2* __restrict__ ep, int* __restrict__ off,
                                            float* __restrict__ dis, int cap2, int N, int E)
{
    __shared__ int h[32], lb[32], cur[32];
    __shared__ float dg[32], sdis[32];
    int g = blockIdx.x, t = threadIdx.x;
    int S1 = g * cap2;
    int S2 = cur2[g];
    int base = gbase[g];
    if (t < 32) { h[t] = 0; dg[t] = 0.f; }
    __syncthreads();
    for (int i = S1 + t; i < S2; i += 256) {
        ull rc = rec2[i];
        int nl = (int)((rc >> 47) & 31);
        atomicAdd(&h[nl], 1);
        atomicAdd(&dg[nl], __half2float(__ushort_as_half((unsigned short)(rc & 0xFFFF))));
    }
    __syncthreads();
    if (t == 0) {
        int run = base;
        for (int k = 0; k < 32; ++k) { lb[k] = run; run += h[k]; }
    }
    __syncthreads();
    if (t < 32) {
        cur[t] = lb[t];
        sdis[t] = 1.0f / sqrtf(dg[t] + 1.0f);   // self-loop included; >= 1 always
        int node = g * 32 + t;
        if (node < N) { off[node] = lb[t]; dis[node] = sdis[t]; }
    }
    if (g == 0 && t == 0) off[N] = E;
    __syncthreads();
    for (int i = S1 + t; i < S2; i += 256) {
        ull rc = rec2[i];
        int nl = (int)((rc >> 47) & 31);
        int p = atomicAdd(&cur[nl], 1);
        float w = __half2float(__ushort_as_half((unsigned short)(rc & 0xFFFF))) * sdis[nl];
        ep[p] = make_int2((int)((rc >> 30) & 0x1FFFF), __float_as_int(w));
    }
}

// ---------------- f32 -> f16 convert with dis[row] pre-scale (stage A table) ----------------
__global__ __launch_bounds__(256) void k_cvt(const float4* __restrict__ in,
                                             const float* __restrict__ dis,
                                             __half2* __restrict__ out, int n4)
{
    int i = blockIdx.x * 256 + threadIdx.x;
    if (i >= n4) return;
    float4 v = in[i];
    float d = dis[i >> 5];          // 32 float4 per row
    __half2 a = __floats2half2_rn(v.x * d, v.y * d);
    __half2 b = __floats2half2_rn(v.z * d, v.w * d);
    float2 pk;
    ((__half2*)&pk)[0] = a;
    ((__half2*)&pk)[1] = b;
    *(float2*)&out[(size_t)i * 2] = pk;
}

// ---------------- all 6 weight transposes in one launch ----------------
__global__ __launch_bounds__(256) void k_wtall(const float* __restrict__ W1, const float* __restrict__ W2,
                                               const float* __restrict__ W3, const float* __restrict__ W4,
                                               const float* __restrict__ W5, const float* __restrict__ W6,
                                               __half* __restrict__ T1, __half* __restrict__ T2,
                                               __half* __restrict__ T3, __half* __restrict__ T4,
                                               __half* __restrict__ T5, __half* __restrict__ T6)
{
    int idx = blockIdx.x * 256 + threadIdx.x;
    const float* W; __half* T; int local, nf;
    if (idx < 81920) {
        int seg = idx >> 14;
        local = idx & 16383;
        nf = 128;
        const float* Ws[5] = {W1, W2, W3, W4, W5};
        __half* Ts[5] = {T1, T2, T3, T4, T5};
        W = Ws[seg]; T = Ts[seg];
    } else if (idx < 90112) {
        local = idx - 81920;
        nf = 64;
        W = W6; T = T6;
    } else return;
    int n = local >> 7, k = local & 127;
    T[local] = __float2half(W[(size_t)k * nf + n]);
}

// ---------------- SpMM: Yh = fp16(aggregate), round-8 proven (4-wide, 2-deep) ----------------
__global__ __launch_bounds__(256) void k_spmm(const __half2* __restrict__ Xh,
                                              const int2* __restrict__ ep,
                                              const int* __restrict__ off,
                                              const float* __restrict__ dis,
                                              __half2* __restrict__ Yh, int n)
{
    int gt = blockIdx.x * 256 + threadIdx.x;
    int node = gt >> 6;
    int lane = threadIdx.x & 63;
    if (node >= n) return;

    float sn = dis[node];                   // self weight (table already carries one dis)
    float2 x0 = __half22float2(Xh[(size_t)node * 64 + lane]);
    float a0x = sn * x0.x, a0y = sn * x0.y;
    float a1x = 0.f, a1y = 0.f;
    float a2x = 0.f, a2y = 0.f;
    float a3x = 0.f, a3y = 0.f;

    const int e0 = off[node];
    const int cnt = off[node + 1] - e0;
    const int2* el = ep + e0;
    const int nb = cnt >> 2;
    int done = 0;

    if (nb >= 2) {
        int2 q0, q1, q2, q3;
        int2 p0 = el[0], p1 = el[1], p2 = el[2], p3 = el[3];
        q0 = el[4]; q1 = el[5]; q2 = el[6]; q3 = el[7];
        __half2 xc0 = Xh[(size_t)p0.x * 64 + lane];
        __half2 xc1 = Xh[(size_t)p1.x * 64 + lane];
        __half2 xc2 = Xh[(size_t)p2.x * 64 + lane];
        __half2 xc3 = Xh[(size_t)p3.x * 64 + lane];
        float wc0 = __int_as_float(p0.y), wc1 = __int_as_float(p1.y);
        float wc2 = __int_as_float(p2.y), wc3 = __int_as_float(p3.y);

        int b;
        #pragma unroll 2
        for (b = 0; b + 2 < nb; ++b) {
            __half2 xn0 = Xh[(size_t)q0.x * 64 + lane];
            __half2 xn1 = Xh[(size_t)q1.x * 64 + lane];
            __half2 xn2 = Xh[(size_t)q2.x * 64 + lane];
            __half2 xn3 = Xh[(size_t)q3.x * 64 + lane];
            float wn0 = __int_as_float(q0.y), wn1 = __int_as_float(q1.y);
            float wn2 = __int_as_float(q2.y), wn3 = __int_as_float(q3.y);
            const int2* eb = el + (size_t)(b + 2) * 4;
            q0 = eb[0]; q1 = eb[1]; q2 = eb[2]; q3 = eb[3];
            float2 f0 = __half22float2(xc0), f1 = __half22float2(xc1);
            float2 f2 = __half22float2(xc2), f3 = __half22float2(xc3);
            a0x += wc0 * f0.x; a0y += wc0 * f0.y;
            a1x += wc1 * f1.x; a1y += wc1 * f1.y;
            a2x += wc2 * f2.x; a2y += wc2 * f2.y;
            a3x += wc3 * f3.x; a3y += wc3 * f3.y;
            xc0 = xn0; xc1 = xn1; xc2 = xn2; xc3 = xn3;
            wc0 = wn0; wc1 = wn1; wc2 = wn2; wc3 = wn3;
        }
        __half2 xn0 = Xh[(size_t)q0.x * 64 + lane];
        __half2 xn1 = Xh[(size_t)q1.x * 64 + lane];
        __half2 xn2 = Xh[(size_t)q2.x * 64 + lane];
        __half2 xn3 = Xh[(size_t)q3.x * 64 + lane];
        float wn0 = __int_as_float(q0.y), wn1 = __int_as_float(q1.y);
        float wn2 = __int_as_float(q2.y), wn3 = __int_as_float(q3.y);
        {
            float2 f0 = __half22float2(xc0), f1 = __half22float2(xc1);
            float2 f2 = __half22float2(xc2), f3 = __half22float2(xc3);
            a0x += wc0 * f0.x; a0y += wc0 * f0.y;
            a1x += wc1 * f1.x; a1y += wc1 * f1.y;
            a2x += wc2 * f2.x; a2y += wc2 * f2.y;
            a3x += wc3 * f3.x; a3y += wc3 * f3.y;
        }
        {
            float2 f0 = __half22float2(xn0), f1 = __half22float2(xn1);
            float2 f2 = __half22float2(xn2), f3 = __half22float2(xn3);
            a0x += wn0 * f0.x; a0y += wn0 * f0.y;
            a1x += wn1 * f1.x; a1y += wn1 * f1.y;
            a2x += wn2 * f2.x; a2y += wn2 * f2.y;
            a3x += wn3 * f3.x; a3y += wn3 * f3.y;
        }
        done = nb * 4;
    }
    for (int e = done; e < cnt; ++e) {
        int2 p = el[e];
        float2 xv = __half22float2(Xh[(size_t)p.x * 64 + lane]);
        float w = __int_as_float(p.y);
        a0x += w * xv.x; a0y += w * xv.y;
    }
    float rx = (a0x + a1x) + (a2x + a3x);
    float ry = (a0y + a1y) + (a2y + a3y);
    Yh[(size_t)node * 64 + lane] = __floats2half2_rn(rx, ry);
}

// ---------------- SpMM64 (stage C): round-8 proven; fused tanh+bias, fp32 out ----------------
__global__ __launch_bounds__(256) void k_spmm64(const __half* __restrict__ Zh,
                                                const int2* __restrict__ ep,
                                                const int* __restrict__ off,
                                                const float* __restrict__ dis,
                                                const float* __restrict__ b6,
                                                float* __restrict__ out, int n)
{
    int gt = blockIdx.x * 256 + threadIdx.x;
    int node = gt >> 6;
    int lane = threadIdx.x & 63;
    if (node >= n) return;

    float sn = dis[node];
    float x0 = __half2float(Zh[(size_t)node * 64 + lane]);
    float a0 = sn * x0, a1 = 0.f, a2 = 0.f, a3 = 0.f;

    const int e0 = off[node];
    const int cnt = off[node + 1] - e0;
    const int2* el = ep + e0;
    const int nb = cnt >> 2;
    int done = 0;

    if (nb >= 2) {
        int2 q0, q1, q2, q3;
        int2 p0 = el[0], p1 = el[1], p2 = el[2], p3 = el[3];
        q0 = el[4]; q1 = el[5]; q2 = el[6]; q3 = el[7];
        __half xc0 = Zh[(size_t)p0.x * 64 + lane];
        __half xc1 = Zh[(size_t)p1.x * 64 + lane];
        __half xc2 = Zh[(size_t)p2.x * 64 + lane];
        __half xc3 = Zh[(size_t)p3.x * 64 + lane];
        float wc0 = __int_as_float(p0.y), wc1 = __int_as_float(p1.y);
        float wc2 = __int_as_float(p2.y), wc3 = __int_as_float(p3.y);

        int b;
        #pragma unroll 2
        for (b = 0; b + 2 < nb; ++b) {
            __half xn0 = Zh[(size_t)q0.x * 64 + lane];
            __half xn1 = Zh[(size_t)q1.x * 64 + lane];
            __half xn2 = Zh[(size_t)q2.x * 64 + lane];
            __half xn3 = Zh[(size_t)q3.x * 64 + lane];
            float wn0 = __int_as_float(q0.y), wn1 = __int_as_float(q1.y);
            float wn2 = __int_as_float(q2.y), wn3 = __int_as_float(q3.y);
            const int2* eb = el + (size_t)(b + 2) * 4;
            q0 = eb[0]; q1 = eb[1]; q2 = eb[2]; q3 = eb[3];
            a0 += wc0 * __half2float(xc0);
            a1 += wc1 * __half2float(xc1);
            a2 += wc2 * __half2float(xc2);
            a3 += wc3 * __half2float(xc3);
            xc0 = xn0; xc1 = xn1; xc2 = xn2; xc3 = xn3;
            wc0 = wn0; wc1 = wn1; wc2 = wn2; wc3 = wn3;
        }
        __half xn0 = Zh[(size_t)q0.x * 64 + lane];
        __half xn1 = Zh[(size_t)q1.x * 64 + lane];
        __half xn2 = Zh[(size_t)q2.x * 64 + lane];
        __half xn3 = Zh[(size_t)q3.x * 64 + lane];
        float wn0 = __int_as_float(q0.y), wn1 = __int_as_float(q1.y);
        float wn2 = __int_as_float(q2.y), wn3 = __int_as_float(q3.y);
        a0 += wc0 * __half2float(xc0);
        a1 += wc1 * __half2float(xc1);
        a2 += wc2 * __half2float(xc2);
        a3 += wc3 * __half2float(xc3);
        a0 += wn0 * __half2float(xn0);
        a1 += wn1 * __half2float(xn1);
        a2 += wn2 * __half2float(xn2);
        a3 += wn3 * __half2float(xn3);
        done = nb * 4;
    }
    for (int e = done; e < cnt; ++e) {
        int2 p = el[e];
        float w = __int_as_float(p.y);
        a0 += w * __half2float(Zh[(size_t)p.x * 64 + lane]);
    }
    float acc = (a0 + a1) + (a2 + a3);
    out[(size_t)node * 64 + lane] = tanhf(fmaf(acc, ZSCALE_COMP, b6[lane]));
}

// fast tanh: 1 - 2/(e^{2x}+1) via v_exp + v_rcp
__device__ __forceinline__ float fast_tanh(float x) {
    float e = __expf(2.0f * x);
    return 1.0f - 2.0f * __builtin_amdgcn_rcpf(e + 1.0f);
}

// ---------------- MFMA GEMM, register-resident B (round-8 proven) ----------------
template <int FOUT, int NW, bool ACT>
__global__ __launch_bounds__(256, 2) void k_mgemm(const __half* __restrict__ Yh,
                                                  float IS, float OS,
                                                  const float* __restrict__ dis,
                                                  const __half* __restrict__ Wt0, const float* __restrict__ B0,
                                                  const __half* __restrict__ Wt1, const float* __restrict__ B1,
                                                  const __half* __restrict__ Wt2, const float* __restrict__ B2,
                                                  __half* __restrict__ Out, int nRows)
{
    constexpr int NF = FOUT / 16;
    constexpr int FPW = NF / 4;
    int tid = threadIdx.x;
    int wv = tid >> 6;
    int lane = tid & 63;
    int lo = lane & 15, hi = lane >> 4;
    int r0 = blockIdx.x * 64;

    const __half* Wts[3] = {Wt0, Wt1, Wt2};
    const float*  Bs[3]  = {B0, B1, B2};

    f16x8 bfr[FPW][NW][4];
    float bias[FPW][NW];
    #pragma unroll
    for (int fp = 0; fp < FPW; ++fp) {
        int f = wv * FPW + fp;
        #pragma unroll
        for (int w = 0; w < NW; ++w) {
            const __half* Bp = Wts[w] + (size_t)(f * 16 + lo) * 128 + hi * 8;
            #pragma unroll
            for (int ks = 0; ks < 4; ++ks)
                bfr[fp][w][ks] = *(const f16x8*)(Bp + ks * 32);
            if constexpr (ACT) bias[fp][w] = Bs[w][f * 16 + lo];
        }
    }

    float disr[4][4];
    if constexpr (ACT) {
        #pragma unroll
        for (int rt = 0; rt < 4; ++rt)
            #pragma unroll
            for (int r = 0; r < 4; ++r) {
                int row = r0 + rt * 16 + hi * 4 + r;
                if (row >= nRows) row = nRows - 1;
                disr[rt][r] = dis[row];
            }
    }

    f16x8 a[4], an[4];
    {
        int row = r0 + lo;
        if (row >= nRows) row = nRows - 1;
        const __half* Ap = Yh + (size_t)row * 128 + hi * 8;
        #pragma unroll
        for (int ks = 0; ks < 4; ++ks) a[ks] = *(const f16x8*)(Ap + ks * 32);
    }

    #pragma unroll
    for (int rt = 0; rt < 4; ++rt) {
        if (rt < 3) {
            int row = r0 + (rt + 1) * 16 + lo;
            if (row >= nRows) row = nRows - 1;
            const __half* Ap = Yh + (size_t)row * 128 + hi * 8;
            #pragma unroll
            for (int ks = 0; ks < 4; ++ks) an[ks] = *(const f16x8*)(Ap + ks * 32);
        }
        #pragma unroll
        for (int fp = 0; fp < FPW; ++fp) {
            f32x4 ac0 = {0.f, 0.f, 0.f, 0.f};
            f32x4 ac1 = {0.f, 0.f, 0.f, 0.f};
            f32x4 ac2 = {0.f, 0.f, 0.f, 0.f};
            #pragma unroll
            for (int ks = 0; ks < 4; ++ks) {
                ac0 = __builtin_amdgcn_mfma_f32_16x16x32_f16(a[ks], bfr[fp][0][ks], ac0, 0, 0, 0);
                if constexpr (NW > 1)
                    ac1 = __builtin_amdgcn_mfma_f32_16x16x32_f16(a[ks], bfr[fp][1][ks], ac1, 0, 0, 0);
                if constexpr (NW > 2)
                    ac2 = __builtin_amdgcn_mfma_f32_16x16x32_f16(a[ks], bfr[fp][2][ks], ac2, 0, 0, 0);
            }
            int c = (wv * FPW + fp) * 16 + lo;
            #pragma unroll
            for (int r = 0; r < 4; ++r) {
                int row = r0 + rt * 16 + hi * 4 + r;
                float v;
                if constexpr (ACT) {
                    v = fast_tanh(fmaf(ac0[r], IS, bias[fp][0]));
                    if constexpr (NW > 1) v *= fast_tanh(fmaf(ac1[r], IS, bias[fp][1]));
                    if constexpr (NW > 2) v *= fast_tanh(fmaf(ac2[r], IS, bias[fp][2]));
                    v *= OS * disr[rt][r];
                } else {
                    v = ac0[r] * OS;
                }
                if (row < nRows)
                    Out[(size_t)row * FOUT + c] = __float2half(v);
            }
        }
        #pragma unroll
        for (int ks = 0; ks < 4; ++ks) a[ks] = an[ks];
    }
}

extern "C" void kernel_launch(void* const* d_in, const int* in_sizes, int n_in,
                              void* d_out, int out_size, void* d_ws, size_t ws_size,
                              hipStream_t stream)
{
    const float* h0 = (const float*)d_in[0];
    const int*   ei = (const int*)d_in[1];
    const float* ew = (const float*)d_in[2];
    const float* W1 = (const float*)d_in[3];  const float* b1 = (const float*)d_in[4];
    const float* W2 = (const float*)d_in[5];  const float* b2 = (const float*)d_in[6];
    const float* W3 = (const float*)d_in[7];  const float* b3 = (const float*)d_in[8];
    const float* W4 = (const float*)d_in[9];  const float* b4 = (const float*)d_in[10];
    const float* W5 = (const float*)d_in[11]; const float* b5 = (const float*)d_in[12];
    const float* W6 = (const float*)d_in[13]; const float* b6 = (const float*)d_in[14];

    const int N = in_sizes[0] / FDIM;
    const int E = in_sizes[2];
    const int* rowp = ei;
    const int* colp = ei + E;

    const int NB1 = (E + CHUNK - 1) / CHUNK;
    // fixed-capacity regions: mean bucket = ~E/49, mean group = ~E/3125; generous slack
    const int cap1 = E / 40;        // 80000 for E=3.2M (mean 65.5K, +57 sigma)
    const int cap2 = E / 2000;      // 1600 for E=3.2M (mean 1024, +18 sigma)

    char* p = (char*)d_ws;
    auto alloc = [&](size_t bytes) -> void* {
        void* r = (void*)p;
        p += (bytes + 255) & ~(size_t)255;
        return r;
    };
    int* cur1  = (int*)alloc((size_t)B1 * 4);
    int* cur2  = (int*)alloc((size_t)NGRP * 4);
    int* gbase = (int*)alloc((size_t)(NGRP + 1) * 4);
    int* off   = (int*)alloc((size_t)(N + 1) * 4);
    float* dis = (float*)alloc((size_t)N * 4);
    ull* rec1  = (ull*)alloc((size_t)B1 * cap1 * 8);    // later aliased by ep
    ull* rec2  = (ull*)alloc((size_t)NGRP * cap2 * 8);  // later aliased by Yh
    __half2* Xh = (__half2*)alloc((size_t)N * FDIM * 2);  // later aliased by Zh
    __half2* Hh = (__half2*)alloc((size_t)N * FDIM * 2);
    __half* W1t = (__half*)alloc((size_t)128 * 128 * 2);
    __half* W2t = (__half*)alloc((size_t)128 * 128 * 2);
    __half* W3t = (__half*)alloc((size_t)128 * 128 * 2);
    __half* W4t = (__half*)alloc((size_t)128 * 128 * 2);
    __half* W5t = (__half*)alloc((size_t)128 * 128 * 2);
    __half* W6t = (__half*)alloc((size_t)64 * 128 * 2);

    int2*    ep = (int2*)rec1;       // rec1 dead after k_p2part
    __half2* Yh = (__half2*)rec2;    // rec2 dead after k_p3
    __half*  Zh = (__half*)Xh;       // Xh dead after stage-A spmm

    // ---- build: 5 kernels, no scans over E-sized count arrays, no memset ----
    k_init<<<(NGRP + 255) / 256, 256, 0, stream>>>(cur1, cur2, cap1, cap2);
    k_p1part<<<NB1, 256, 0, stream>>>(colp, rowp, ew, cur1, rec1, E);
    k_p2part<<<B1 * MAXC2, 256, 0, stream>>>(rec1, cur1, cur2, rec2, cap1);
    k_gscan<<<1, 1024, 0, stream>>>(cur2, gbase, cap2);
    k_p3<<<NGRP, 256, 0, stream>>>(rec2, cur2, gbase, ep, off, dis, cap2, N, E);

    // ---- dense prep ----
    k_cvt<<<(N * 32 + 255) / 256, 256, 0, stream>>>((const float4*)h0, dis, Xh, N * 32);
    k_wtall<<<352, 256, 0, stream>>>(W1, W2, W3, W4, W5, W6, W1t, W2t, W3t, W4t, W5t, W6t);

    const int sb = (N + 3) / 4;     // 4 waves (nodes) per 256-thread block
    const int gb = (N + 63) / 64;   // 64-row tiles

    // Stage A: Yh = agg(Xh) ; Hh = HSCALE*dis*tanh(YhW1+b1)*tanh(YhW2+b2)*tanh(YhW3+b3)
    k_spmm<<<sb, 256, 0, stream>>>(Xh, ep, off, dis, Yh, N);
    k_mgemm<128, 3, true><<<gb, 256, 0, stream>>>((const __half*)Yh, 1.0f, HSCALE, dis,
        W1t, b1, W2t, b2, W3t, b3, (__half*)Hh, N);
    // Stage B: Yh = agg(Hh) ; Hh = HSCALE*dis*tanh(2^-14 YhW4+b4)*tanh(2^-14 YhW5+b5)
    k_spmm<<<sb, 256, 0, stream>>>(Hh, ep, off, dis, Yh, N);
    k_mgemm<128, 2, true><<<gb, 256, 0, stream>>>((const __half*)Yh, HSCALE_INV, HSCALE, dis,
        W4t, b4, W5t, b5, nullptr, nullptr, (__half*)Hh, N);
    // Stage C: project first (Zh = ZSCALE * Hh W6, 64 features), then aggregate+tanh -> out
    k_mgemm<64, 1, false><<<gb, 256, 0, stream>>>((const __half*)Hh, 1.0f, ZSCALE, nullptr,
        W6t, b6, nullptr, nullptr, nullptr, nullptr, Zh, N);
    k_spmm64<<<sb, 256, 0, stream>>>(Zh, ep, off, dis, b6, (float*)d_out, N);
}

// Round 11
// 492.767 us; speedup vs baseline: 1.0606x; 1.0202x over previous
//
#include <hip/hip_runtime.h>
#include <hip/hip_bf16.h>
#include <hip/hip_fp16.h>

constexpr int FDIM = 128;
#define HSCALE 16384.0f         // 2^14: |h|<1 -> scaled <16384 <= 65504, always safe
#define HSCALE_INV (1.0f/16384.0f)
#define ZSCALE 0.125f           // extra headroom for Zh = Hh @ W6
#define ZSCALE_COMP (HSCALE_INV * 8.0f)

typedef _Float16 f16x8 __attribute__((ext_vector_type(8)));
typedef float f32x4 __attribute__((ext_vector_type(4)));
typedef unsigned long long ull;

// ===================== atomic-reserved CSR build (2 partition passes) =====================
// record: [col:17 @47][row:17 @30][ew_f16 @0]
constexpr int CHUNK = 4096;
constexpr int B1 = 64;
constexpr int B2 = 64;
constexpr int NGRP = B1 * B2;   // 4096
constexpr int MAXC2 = 20;

__global__ __launch_bounds__(256) void k_init(int* __restrict__ cur1,
                                              int* __restrict__ cur2,
                                              int cap1, int cap2)
{
    int i = blockIdx.x * 256 + threadIdx.x;
    if (i < B1) cur1[i] = i * cap1;
    if (i < NGRP) cur2[i] = i * cap2;
}

// pass 1: chunk -> 64 coarse buckets.
__global__ __launch_bounds__(256) void k_p1part(const int* __restrict__ col,
                                                const int* __restrict__ row,
                                                const float* __restrict__ ew,
                                                int* __restrict__ cur1,
                                                ull* __restrict__ rec1, int E)
{
    __shared__ ull stage[CHUNK];
    __shared__ int hcnt[B1], lb[B1], gb[B1], lcur[B1];
    int blk = blockIdx.x, t = threadIdx.x;
    if (t < B1) hcnt[t] = 0;
    __syncthreads();
    int base = blk * CHUNK;
    ull rc[16];
    #pragma unroll
    for (int it = 0; it < 16; ++it) {
        int g = base + it * 256 + t;
        if (g < E) {
            int c = col[g], r = row[g];
            rc[it] = ((ull)c << 47) | ((ull)r << 30) |
                     (ull)__half_as_ushort(__float2half(ew[g]));
            atomicAdd(&hcnt[c >> 11], 1);
        } else rc[it] = ~0ull;
    }
    __syncthreads();
    if (t == 0) {
        int run = 0;
        for (int b = 0; b < B1; ++b) { lb[b] = run; run += hcnt[b]; }
    }
    __syncthreads();
    if (t < B1) { lcur[t] = lb[t]; gb[t] = atomicAdd(&cur1[t], hcnt[t]); }
    __syncthreads();
    #pragma unroll
    for (int it = 0; it < 16; ++it) {
        if (rc[it] != ~0ull) {
            int b = (int)(rc[it] >> 58);
            stage[atomicAdd(&lcur[b], 1)] = rc[it];
        }
    }
    __syncthreads();
    int here = min(CHUNK, E - base);
    for (int j = t; j < here; j += 256) {
        ull v = stage[j];
        int b = (int)(v >> 58);
        rec1[gb[b] + (j - lb[b])] = v;
    }
}

// pass 2: within each coarse bucket, partition chunks into 64 sub-buckets (groups).
__global__ __launch_bounds__(256) void k_p2part(const ull* __restrict__ rec1,
                                                const int* __restrict__ cur1,
                                                int* __restrict__ cur2,
                                                ull* __restrict__ rec2,
                                                int cap1)
{
    __shared__ ull stage[CHUNK];
    __shared__ int hcnt[B2], lb[B2], gb[B2], lcur[B2];
    int b = blockIdx.x / MAXC2, ci = blockIdx.x % MAXC2, t = threadIdx.x;
    int S1 = b * cap1;
    int size = cur1[b] - S1;
    for (int c = ci; c * CHUNK < size; c += MAXC2) {
        int cb = S1 + c * CHUNK;
        int m = min(CHUNK, size - c * CHUNK);
        __syncthreads();
        if (t < B2) hcnt[t] = 0;
        __syncthreads();
        ull rc[16];
        #pragma unroll
        for (int it = 0; it < 16; ++it) {
            int j = it * 256 + t;
            if (j < m) {
                ull v = rec1[cb + j];
                rc[it] = v;
                atomicAdd(&hcnt[(int)((v >> 52) & 63)], 1);
            } else rc[it] = ~0ull;
        }
        __syncthreads();
        if (t == 0) {
            int run = 0;
            for (int s = 0; s < B2; ++s) { lb[s] = run; run += hcnt[s]; }
        }
        __syncthreads();
        if (t < B2) { lcur[t] = lb[t]; gb[t] = atomicAdd(&cur2[b * B2 + t], hcnt[t]); }
        __syncthreads();
        #pragma unroll
        for (int it = 0; it < 16; ++it) {
            if (rc[it] != ~0ull) {
                int s = (int)((rc[it] >> 52) & 63);
                stage[atomicAdd(&lcur[s], 1)] = rc[it];
            }
        }
        __syncthreads();
        for (int j = t; j < m; j += 256) {
            ull v = stage[j];
            int s = (int)((v >> 52) & 63);
            rec2[gb[s] + (j - lb[s])] = v;
        }
    }
}

// one-block exclusive scan of the 4096 group sizes -> compact output bases
__global__ __launch_bounds__(1024) void k_gscan(const int* __restrict__ cur2,
                                                int* __restrict__ gbase, int cap2)
{
    __shared__ int s[1024];
    __shared__ int carry;
    int t = threadIdx.x;
    if (t == 0) carry = 0;
    __syncthreads();
    for (int tile = 0; tile < 4; ++tile) {
        int g = tile * 1024 + t;
        int v = cur2[g] - g * cap2;
        s[t] = v;
        __syncthreads();
        for (int o = 1; o < 1024; o <<= 1) {
            int u = (t >= o) ? s[t - o] : 0;
            __syncthreads();
            s[t] += u;
            __syncthreads();
        }
        gbase[g] = carry + s[t] - v;    // exclusive
        __syncthreads();
        if (t == 1023) carry += s[t];
        __syncthreads();
    }
}

// final: counting sort per 32-node group; emits compact ep=(row, ew*dis[col]), off, dis
__global__ __launch_bounds__(256) void k_p3(const ull* __restrict__ rec2,
                                            const int* __restrict__ cur2,
                                            const int* __restrict__ gbase,
                                            int2* __restrict__ ep, int* __restrict__ off,
                                            float* __restrict__ dis, int cap2, int N, int E)
{
    __shared__ int h[32], lb[32], cur[32];
    __shared__ float dg[32], sdis[32];
    int g = blockIdx.x, t = threadIdx.x;
    int S1 = g * cap2;
    int S2 = cur2[g];
    int base = gbase[g];
    if (t < 32) { h[t] = 0; dg[t] = 0.f; }
    __syncthreads();
    for (int i = S1 + t; i < S2; i += 256) {
        ull rc = rec2[i];
        int nl = (int)((rc >> 47) & 31);
        atomicAdd(&h[nl], 1);
        atomicAdd(&dg[nl], __half2float(__ushort_as_half((unsigned short)(rc & 0xFFFF))));
    }
    __syncthreads();
    if (t == 0) {
        int run = base;
        for (int k = 0; k < 32; ++k) { lb[k] = run; run += h[k]; }
    }
    __syncthreads();
    if (t < 32) {
        cur[t] = lb[t];
        sdis[t] = 1.0f / sqrtf(dg[t] + 1.0f);   // self-loop included; >= 1 always
        int node = g * 32 + t;
        if (node < N) { off[node] = lb[t]; dis[node] = sdis[t]; }
    }
    if (g == 0 && t == 0) off[N] = E;
    __syncthreads();
    for (int i = S1 + t; i < S2; i += 256) {
        ull rc = rec2[i];
        int nl = (int)((rc >> 47) & 31);
        int p = atomicAdd(&cur[nl], 1);
        float w = __half2float(__ushort_as_half((unsigned short)(rc & 0xFFFF))) * sdis[nl];
        ep[p] = make_int2((int)((rc >> 30) & 0x1FFFF), __float_as_int(w));
    }
}

// ---------------- f32 -> f16 convert with dis[row] pre-scale (stage A table) ----------------
__global__ __launch_bounds__(256) void k_cvt(const float4* __restrict__ in,
                                             const float* __restrict__ dis,
                                             __half2* __restrict__ out, int n4)
{
    int i = blockIdx.x * 256 + threadIdx.x;
    if (i >= n4) return;
    float4 v = in[i];
    float d = dis[i >> 5];          // 32 float4 per row
    __half2 a = __floats2half2_rn(v.x * d, v.y * d);
    __half2 b = __floats2half2_rn(v.z * d, v.w * d);
    float2 pk;
    ((__half2*)&pk)[0] = a;
    ((__half2*)&pk)[1] = b;
    *(float2*)&out[(size_t)i * 2] = pk;
}

// ---------------- all 6 weight transposes in one launch ----------------
__global__ __launch_bounds__(256) void k_wtall(const float* __restrict__ W1, const float* __restrict__ W2,
                                               const float* __restrict__ W3, const float* __restrict__ W4,
                                               const float* __restrict__ W5, const float* __restrict__ W6,
                                               __half* __restrict__ T1, __half* __restrict__ T2,
                                               __half* __restrict__ T3, __half* __restrict__ T4,
                                               __half* __restrict__ T5, __half* __restrict__ T6)
{
    int idx = blockIdx.x * 256 + threadIdx.x;
    const float* W; __half* T; int local, nf;
    if (idx < 81920) {
        int seg = idx >> 14;
        local = idx & 16383;
        nf = 128;
        const float* Ws[5] = {W1, W2, W3, W4, W5};
        __half* Ts[5] = {T1, T2, T3, T4, T5};
        W = Ws[seg]; T = Ts[seg];
    } else if (idx < 90112) {
        local = idx - 81920;
        nf = 64;
        W = W6; T = T6;
    } else return;
    int n = local >> 7, k = local & 127;
    T[local] = __float2half(W[(size_t)k * nf + n]);
}

// ---------------- SpMM: Yh = fp16(aggregate), round-8 proven (4-wide, 2-deep) ----------------
__global__ __launch_bounds__(256) void k_spmm(const __half2* __restrict__ Xh,
                                              const int2* __restrict__ ep,
                                              const int* __restrict__ off,
                                              const float* __restrict__ dis,
                                              __half2* __restrict__ Yh, int n)
{
    int gt = blockIdx.x * 256 + threadIdx.x;
    int node = gt >> 6;
    int lane = threadIdx.x & 63;
    if (node >= n) return;

    float sn = dis[node];                   // self weight (table already carries one dis)
    float2 x0 = __half22float2(Xh[(size_t)node * 64 + lane]);
    float a0x = sn * x0.x, a0y = sn * x0.y;
    float a1x = 0.f, a1y = 0.f;
    float a2x = 0.f, a2y = 0.f;
    float a3x = 0.f, a3y = 0.f;

    const int e0 = off[node];
    const int cnt = off[node + 1] - e0;
    const int2* el = ep + e0;
    const int nb = cnt >> 2;
    int done = 0;

    if (nb >= 2) {
        int2 q0, q1, q2, q3;
        int2 p0 = el[0], p1 = el[1], p2 = el[2], p3 = el[3];
        q0 = el[4]; q1 = el[5]; q2 = el[6]; q3 = el[7];
        __half2 xc0 = Xh[(size_t)p0.x * 64 + lane];
        __half2 xc1 = Xh[(size_t)p1.x * 64 + lane];
        __half2 xc2 = Xh[(size_t)p2.x * 64 + lane];
        __half2 xc3 = Xh[(size_t)p3.x * 64 + lane];
        float wc0 = __int_as_float(p0.y), wc1 = __int_as_float(p1.y);
        float wc2 = __int_as_float(p2.y), wc3 = __int_as_float(p3.y);

        int b;
        #pragma unroll 2
        for (b = 0; b + 2 < nb; ++b) {
            __half2 xn0 = Xh[(size_t)q0.x * 64 + lane];
            __half2 xn1 = Xh[(size_t)q1.x * 64 + lane];
            __half2 xn2 = Xh[(size_t)q2.x * 64 + lane];
            __half2 xn3 = Xh[(size_t)q3.x * 64 + lane];
            float wn0 = __int_as_float(q0.y), wn1 = __int_as_float(q1.y);
            float wn2 = __int_as_float(q2.y), wn3 = __int_as_float(q3.y);
            const int2* eb = el + (size_t)(b + 2) * 4;
            q0 = eb[0]; q1 = eb[1]; q2 = eb[2]; q3 = eb[3];
            float2 f0 = __half22float2(xc0), f1 = __half22float2(xc1);
            float2 f2 = __half22float2(xc2), f3 = __half22float2(xc3);
            a0x += wc0 * f0.x; a0y += wc0 * f0.y;
            a1x += wc1 * f1.x; a1y += wc1 * f1.y;
            a2x += wc2 * f2.x; a2y += wc2 * f2.y;
            a3x += wc3 * f3.x; a3y += wc3 * f3.y;
            xc0 = xn0; xc1 = xn1; xc2 = xn2; xc3 = xn3;
            wc0 = wn0; wc1 = wn1; wc2 = wn2; wc3 = wn3;
        }
        __half2 xn0 = Xh[(size_t)q0.x * 64 + lane];
        __half2 xn1 = Xh[(size_t)q1.x * 64 + lane];
        __half2 xn2 = Xh[(size_t)q2.x * 64 + lane];
        __half2 xn3 = Xh[(size_t)q3.x * 64 + lane];
        float wn0 = __int_as_float(q0.y), wn1 = __int_as_float(q1.y);
        float wn2 = __int_as_float(q2.y), wn3 = __int_as_float(q3.y);
        {
            float2 f0 = __half22float2(xc0), f1 = __half22float2(xc1);
            float2 f2 = __half22float2(xc2), f3 = __half22float2(xc3);
            a0x += wc0 * f0.x; a0y += wc0 * f0.y;
            a1x += wc1 * f1.x; a1y += wc1 * f1.y;
            a2x += wc2 * f2.x; a2y += wc2 * f2.y;
            a3x += wc3 * f3.x; a3y += wc3 * f3.y;
        }
        {
            float2 f0 = __half22float2(xn0), f1 = __half22float2(xn1);
            float2 f2 = __half22float2(xn2), f3 = __half22float2(xn3);
            a0x += wn0 * f0.x; a0y += wn0 * f0.y;
            a1x += wn1 * f1.x; a1y += wn1 * f1.y;
            a2x += wn2 * f2.x; a2y += wn2 * f2.y;
            a3x += wn3 * f3.x; a3y += wn3 * f3.y;
        }
        done = nb * 4;
    }
    for (int e = done; e < cnt; ++e) {
        int2 p = el[e];
        float2 xv = __half22float2(Xh[(size_t)p.x * 64 + lane]);
        float w = __int_as_float(p.y);
        a0x += w * xv.x; a0y += w * xv.y;
    }
    float rx = (a0x + a1x) + (a2x + a3x);
    float ry = (a0y + a1y) + (a2y + a3y);
    Yh[(size_t)node * 64 + lane] = __floats2half2_rn(rx, ry);
}

// ---------------- SpMM64 (stage C): 4 edges per wave-step ----------------
// 4 groups of 16 lanes; group g owns edge 4b+g; each lane gathers 8B (4 features,
// 16 lanes x 8B = full 128B row). Cross-group merge via shfl_xor(16,32);
// lanes 0-15 apply tanh+bias and write float4. 2-deep gather pipeline.
__global__ __launch_bounds__(256) void k_spmm64(const __half* __restrict__ Zh,
                                                const int2* __restrict__ ep,
                                                const int* __restrict__ off,
                                                const float* __restrict__ dis,
                                                const float* __restrict__ b6,
                                                float* __restrict__ out, int n)
{
    int gt = blockIdx.x * 256 + threadIdx.x;
    int node = gt >> 6;
    int lane = threadIdx.x & 63;
    if (node >= n) return;
    const int grp = lane >> 4;
    const int l15 = lane & 15;
    const char* Zb = (const char*)Zh;
    const unsigned loff = (unsigned)l15 << 3;    // 8B per lane

    f32x4 acc0 = {0.f, 0.f, 0.f, 0.f};
    f32x4 acc1 = {0.f, 0.f, 0.f, 0.f};

    if (grp == 0) {                              // self-loop term
        float sn = dis[node];
        float2 raw = *(const float2*)(Zb + (((unsigned)node << 7) + loff));
        float2 f0 = __half22float2(((const __half2*)&raw)[0]);
        float2 f1 = __half22float2(((const __half2*)&raw)[1]);
        acc0[0] = sn * f0.x; acc0[1] = sn * f0.y;
        acc0[2] = sn * f1.x; acc0[3] = sn * f1.y;
    }

    const int e0 = off[node];
    const int cnt = off[node + 1] - e0;
    const int2* el = ep + e0;
    const int nb = cnt >> 2;                     // batches of 4 edges
    int done = 0;

    if (nb >= 2) {
        int2 ec = el[grp];
        float2 xc = *(const float2*)(Zb + (((unsigned)ec.x << 7) + loff));
        int2 en = el[4 + grp];
        float2 xn;

        #pragma unroll 2
        for (int b = 0; b + 2 < nb; ++b) {
            xn = *(const float2*)(Zb + (((unsigned)en.x << 7) + loff));
            int2 e2 = el[(b + 2) * 4 + grp];
            float w = __int_as_float(ec.y);
            float2 f0 = __half22float2(((const __half2*)&xc)[0]);
            float2 f1 = __half22float2(((const __half2*)&xc)[1]);
            if (b & 1) {
                acc1[0] += w * f0.x; acc1[1] += w * f0.y;
                acc1[2] += w * f1.x; acc1[3] += w * f1.y;
            } else {
                acc0[0] += w * f0.x; acc0[1] += w * f0.y;
                acc0[2] += w * f1.x; acc0[3] += w * f1.y;
            }
            ec = en; xc = xn; en = e2;
        }
        // epilogue: batch nb-2 (ec/xc ready) then nb-1 (en, gather now)
        xn = *(const float2*)(Zb + (((unsigned)en.x << 7) + loff));
        {
            float w = __int_as_float(ec.y);
            float2 f0 = __half22float2(((const __half2*)&xc)[0]);
            float2 f1 = __half22float2(((const __half2*)&xc)[1]);
            acc0[0] += w * f0.x; acc0[1] += w * f0.y;
            acc0[2] += w * f1.x; acc0[3] += w * f1.y;
        }
        {
            float w = __int_as_float(en.y);
            float2 f0 = __half22float2(((const __half2*)&xn)[0]);
            float2 f1 = __half22float2(((const __half2*)&xn)[1]);
            acc1[0] += w * f0.x; acc1[1] += w * f0.y;
            acc1[2] += w * f1.x; acc1[3] += w * f1.y;
        }
        done = nb * 4;
    }
    // tail: 0..3 leftover edges, group-parallel with clamp
    for (int e = done; e < cnt; e += 4) {
        int idx = e + grp;
        int2 pe = el[min(idx, cnt - 1)];
        float w = (idx < cnt) ? __int_as_float(pe.y) : 0.f;
        float2 raw = *(const float2*)(Zb + (((unsigned)pe.x << 7) + loff));
        float2 f0 = __half22float2(((const __half2*)&raw)[0]);
        float2 f1 = __half22float2(((const __half2*)&raw)[1]);
        acc0[0] += w * f0.x; acc0[1] += w * f0.y;
        acc0[2] += w * f1.x; acc0[3] += w * f1.y;
    }

    f32x4 r;
    #pragma unroll
    for (int j = 0; j < 4; ++j) {
        r[j] = acc0[j] + acc1[j];
        r[j] += __shfl_xor(r[j], 16);
        r[j] += __shfl_xor(r[j], 32);
    }
    if (lane < 16) {
        float4 bb = *(const float4*)(b6 + 4 * l15);
        float4 o;
        o.x = tanhf(fmaf(r[0], ZSCALE_COMP, bb.x));
        o.y = tanhf(fmaf(r[1], ZSCALE_COMP, bb.y));
        o.z = tanhf(fmaf(r[2], ZSCALE_COMP, bb.z));
        o.w = tanhf(fmaf(r[3], ZSCALE_COMP, bb.w));
        *(float4*)((char*)out + (((size_t)node << 8) + ((unsigned)l15 << 4))) = o;
    }
}

// fast tanh: 1 - 2/(e^{2x}+1) via v_exp + v_rcp
__device__ __forceinline__ float fast_tanh(float x) {
    float e = __expf(2.0f * x);
    return 1.0f - 2.0f * __builtin_amdgcn_rcpf(e + 1.0f);
}

// ---------------- MFMA GEMM, register-resident B (round-8 proven) ----------------
template <int FOUT, int NW, bool ACT>
__global__ __launch_bounds__(256, 2) void k_mgemm(const __half* __restrict__ Yh,
                                                  float IS, float OS,
                                                  const float* __restrict__ dis,
                                                  const __half* __restrict__ Wt0, const float* __restrict__ B0,
                                                  const __half* __restrict__ Wt1, const float* __restrict__ B1,
                                                  const __half* __restrict__ Wt2, const float* __restrict__ B2,
                                                  __half* __restrict__ Out, int nRows)
{
    constexpr int NF = FOUT / 16;
    constexpr int FPW = NF / 4;
    int tid = threadIdx.x;
    int wv = tid >> 6;
    int lane = tid & 63;
    int lo = lane & 15, hi = lane >> 4;
    int r0 = blockIdx.x * 64;

    const __half* Wts[3] = {Wt0, Wt1, Wt2};
    const float*  Bs[3]  = {B0, B1, B2};

    f16x8 bfr[FPW][NW][4];
    float bias[FPW][NW];
    #pragma unroll
    for (int fp = 0; fp < FPW; ++fp) {
        int f = wv * FPW + fp;
        #pragma unroll
        for (int w = 0; w < NW; ++w) {
            const __half* Bp = Wts[w] + (size_t)(f * 16 + lo) * 128 + hi * 8;
            #pragma unroll
            for (int ks = 0; ks < 4; ++ks)
                bfr[fp][w][ks] = *(const f16x8*)(Bp + ks * 32);
            if constexpr (ACT) bias[fp][w] = Bs[w][f * 16 + lo];
        }
    }

    float disr[4][4];
    if constexpr (ACT) {
        #pragma unroll
        for (int rt = 0; rt < 4; ++rt)
            #pragma unroll
            for (int r = 0; r < 4; ++r) {
                int row = r0 + rt * 16 + hi * 4 + r;
                if (row >= nRows) row = nRows - 1;
                disr[rt][r] = dis[row];
            }
    }

    f16x8 a[4], an[4];
    {
        int row = r0 + lo;
        if (row >= nRows) row = nRows - 1;
        const __half* Ap = Yh + (size_t)row * 128 + hi * 8;
        #pragma unroll
        for (int ks = 0; ks < 4; ++ks) a[ks] = *(const f16x8*)(Ap + ks * 32);
    }

    #pragma unroll
    for (int rt = 0; rt < 4; ++rt) {
        if (rt < 3) {
            int row = r0 + (rt + 1) * 16 + lo;
            if (row >= nRows) row = nRows - 1;
            const __half* Ap = Yh + (size_t)row * 128 + hi * 8;
            #pragma unroll
            for (int ks = 0; ks < 4; ++ks) an[ks] = *(const f16x8*)(Ap + ks * 32);
        }
        #pragma unroll
        for (int fp = 0; fp < FPW; ++fp) {
            f32x4 ac0 = {0.f, 0.f, 0.f, 0.f};
            f32x4 ac1 = {0.f, 0.f, 0.f, 0.f};
            f32x4 ac2 = {0.f, 0.f, 0.f, 0.f};
            #pragma unroll
            for (int ks = 0; ks < 4; ++ks) {
                ac0 = __builtin_amdgcn_mfma_f32_16x16x32_f16(a[ks], bfr[fp][0][ks], ac0, 0, 0, 0);
                if constexpr (NW > 1)
                    ac1 = __builtin_amdgcn_mfma_f32_16x16x32_f16(a[ks], bfr[fp][1][ks], ac1, 0, 0, 0);
                if constexpr (NW > 2)
                    ac2 = __builtin_amdgcn_mfma_f32_16x16x32_f16(a[ks], bfr[fp][2][ks], ac2, 0, 0, 0);
            }
            int c = (wv * FPW + fp) * 16 + lo;
            #pragma unroll
            for (int r = 0; r < 4; ++r) {
                int row = r0 + rt * 16 + hi * 4 + r;
                float v;
                if constexpr (ACT) {
                    v = fast_tanh(fmaf(ac0[r], IS, bias[fp][0]));
                    if constexpr (NW > 1) v *= fast_tanh(fmaf(ac1[r], IS, bias[fp][1]));
                    if constexpr (NW > 2) v *= fast_tanh(fmaf(ac2[r], IS, bias[fp][2]));
                    v *= OS * disr[rt][r];
                } else {
                    v = ac0[r] * OS;
                }
                if (row < nRows)
                    Out[(size_t)row * FOUT + c] = __float2half(v);
            }
        }
        #pragma unroll
        for (int ks = 0; ks < 4; ++ks) a[ks] = an[ks];
    }
}

extern "C" void kernel_launch(void* const* d_in, const int* in_sizes, int n_in,
                              void* d_out, int out_size, void* d_ws, size_t ws_size,
                              hipStream_t stream)
{
    const float* h0 = (const float*)d_in[0];
    const int*   ei = (const int*)d_in[1];
    const float* ew = (const float*)d_in[2];
    const float* W1 = (const float*)d_in[3];  const float* b1 = (const float*)d_in[4];
    const float* W2 = (const float*)d_in[5];  const float* b2 = (const float*)d_in[6];
    const float* W3 = (const float*)d_in[7];  const float* b3 = (const float*)d_in[8];
    const float* W4 = (const float*)d_in[9];  const float* b4 = (const float*)d_in[10];
    const float* W5 = (const float*)d_in[11]; const float* b5 = (const float*)d_in[12];
    const float* W6 = (const float*)d_in[13]; const float* b6 = (const float*)d_in[14];

    const int N = in_sizes[0] / FDIM;
    const int E = in_sizes[2];
    const int* rowp = ei;
    const int* colp = ei + E;

    const int NB1 = (E + CHUNK - 1) / CHUNK;
    const int cap1 = E / 40;        // 80000 for E=3.2M (mean 65.5K)
    const int cap2 = E / 2000;      // 1600 for E=3.2M (mean 1024)

    char* p = (char*)d_ws;
    auto alloc = [&](size_t bytes) -> void* {
        void* r = (void*)p;
        p += (bytes + 255) & ~(size_t)255;
        return r;
    };
    int* cur1  = (int*)alloc((size_t)B1 * 4);
    int* cur2  = (int*)alloc((size_t)NGRP * 4);
    int* gbase = (int*)alloc((size_t)(NGRP + 1) * 4);
    int* off   = (int*)alloc((size_t)(N + 1) * 4);
    float* dis = (float*)alloc((size_t)N * 4);
    ull* rec1  = (ull*)alloc((size_t)B1 * cap1 * 8);    // later aliased by ep
    ull* rec2  = (ull*)alloc((size_t)NGRP * cap2 * 8);  // later aliased by Yh
    __half2* Xh = (__half2*)alloc((size_t)N * FDIM * 2);  // later aliased by Zh
    __half2* Hh = (__half2*)alloc((size_t)N * FDIM * 2);
    __half* W1t = (__half*)alloc((size_t)128 * 128 * 2);
    __half* W2t = (__half*)alloc((size_t)128 * 128 * 2);
    __half* W3t = (__half*)alloc((size_t)128 * 128 * 2);
    __half* W4t = (__half*)alloc((size_t)128 * 128 * 2);
    __half* W5t = (__half*)alloc((size_t)128 * 128 * 2);
    __half* W6t = (__half*)alloc((size_t)64 * 128 * 2);

    int2*    ep = (int2*)rec1;       // rec1 dead after k_p2part
    __half2* Yh = (__half2*)rec2;    // rec2 dead after k_p3
    __half*  Zh = (__half*)Xh;       // Xh dead after stage-A spmm

    // ---- build: 5 kernels, no E-sized scans, no memset ----
    k_init<<<(NGRP + 255) / 256, 256, 0, stream>>>(cur1, cur2, cap1, cap2);
    k_p1part<<<NB1, 256, 0, stream>>>(colp, rowp, ew, cur1, rec1, E);
    k_p2part<<<B1 * MAXC2, 256, 0, stream>>>(rec1, cur1, cur2, rec2, cap1);
    k_gscan<<<1, 1024, 0, stream>>>(cur2, gbase, cap2);
    k_p3<<<NGRP, 256, 0, stream>>>(rec2, cur2, gbase, ep, off, dis, cap2, N, E);

    // ---- dense prep ----
    k_cvt<<<(N * 32 + 255) / 256, 256, 0, stream>>>((const float4*)h0, dis, Xh, N * 32);
    k_wtall<<<352, 256, 0, stream>>>(W1, W2, W3, W4, W5, W6, W1t, W2t, W3t, W4t, W5t, W6t);

    const int sb = (N + 3) / 4;     // 4 waves (nodes) per 256-thread block
    const int gb = (N + 63) / 64;   // 64-row tiles

    // Stage A: Yh = agg(Xh) ; Hh = HSCALE*dis*tanh(YhW1+b1)*tanh(YhW2+b2)*tanh(YhW3+b3)
    k_spmm<<<sb, 256, 0, stream>>>(Xh, ep, off, dis, Yh, N);
    k_mgemm<128, 3, true><<<gb, 256, 0, stream>>>((const __half*)Yh, 1.0f, HSCALE, dis,
        W1t, b1, W2t, b2, W3t, b3, (__half*)Hh, N);
    // Stage B: Yh = agg(Hh) ; Hh = HSCALE*dis*tanh(2^-14 YhW4+b4)*tanh(2^-14 YhW5+b5)
    k_spmm<<<sb, 256, 0, stream>>>(Hh, ep, off, dis, Yh, N);
    k_mgemm<128, 2, true><<<gb, 256, 0, stream>>>((const __half*)Yh, HSCALE_INV, HSCALE, dis,
        W4t, b4, W5t, b5, nullptr, nullptr, (__half*)Hh, N);
    // Stage C: project first (Zh = ZSCALE * Hh W6, 64 features), then aggregate+tanh -> out
    k_mgemm<64, 1, false><<<gb, 256, 0, stream>>>((const __half*)Hh, 1.0f, ZSCALE, nullptr,
        W6t, b6, nullptr, nullptr, nullptr, nullptr, Zh, N);
    k_spmm64<<<sb, 256, 0, stream>>>(Zh, ep, off, dis, b6, (float*)d_out, N);
}